// Round 3
// baseline (116.992 us; speedup 1.0000x reference)
//
#include <hip/hip_runtime.h>

#define BATCH 16
#define NPTS  4096
#define TOT   (BATCH * NPTS)   // 65536 points per tensor
#define QSEG  4                // Q split into 4 segments
#define QLEN  (NPTS / QSEG)    // 1024 points per segment

typedef float f2 __attribute__((ext_vector_type(2)));

// packed dual-fp32 fma: d = {a.lo*b.lo+c.lo, a.hi*b.hi+c.hi}
#define PKFMA(d, a, b, c) \
    asm("v_pk_fma_f32 %0, %1, %2, %3" : "=v"(d) : "v"(a), "v"(b), "v"(c))
// 3-input min folded into the accumulator chain
#define MIN3(acc, u, v) \
    asm("v_min3_f32 %0, %1, %2, %0" : "+v"(acc) : "v"(u), "v"(v))

// Pack both tensors into pair-SoA layout: for point-pair gp (points 2gp,2gp+1):
//   pkf[gp*8 + {0,1}] = x pair, {2,3} = y pair, {4,5} = z pair, {6,7} = |q|^2 pair
// Layout over [2][BATCH][NPTS] point ids (slot 0 = x tensor, 1 = y tensor).
// Also zeroes the output scalar (stream-ordered before pass2's atomics).
__global__ __launch_bounds__(256) void pack_kernel(const float* __restrict__ x,
                                                   const float* __restrict__ y,
                                                   float* __restrict__ pkf,
                                                   float* __restrict__ out) {
    int idx = blockIdx.x * 256 + threadIdx.x;       // 0 .. 2*TOT-1
    if (idx == 0) out[0] = 0.0f;
    const float* src = (idx < TOT) ? x : y;
    int r = (idx < TOT) ? idx : (idx - TOT);
    float a = src[r * 3 + 0];
    float b = src[r * 3 + 1];
    float c = src[r * 3 + 2];
    float w = fmaf(a, a, fmaf(b, b, c * c));
    int gp = idx >> 1, h = idx & 1;
    pkf[gp * 8 + 0 + h] = a;
    pkf[gp * 8 + 2 + h] = b;
    pkf[gp * 8 + 4 + h] = c;
    pkf[gp * 8 + 6 + h] = w;
}

// Pass 1: block = (dir, batch, 256-row chunk, q-segment). Each thread owns one
// P point and scans its 1024-point Q segment with packed-fp32 math:
// 2 points cost 3 v_pk_fma_f32 + 1 v_min3_f32 (2.0 VALU/pair).
// Q loads forced to VMEM/VGPR (shfl-perturbed base) -> no SGPR operand limits.
// Partial min written coalesced to part[qseg][pidx].
__global__ __launch_bounds__(256, 8) void chamfer_pass1(const float* __restrict__ pkf,
                                                        float* __restrict__ part) {
    int blk   = blockIdx.x;        // 0..2047
    int qseg  = blk & 3;
    int t     = blk >> 2;
    int dir   = t >> 8;            // 0: P=x,Q=y ; 1: P=y,Q=x
    int bb    = (t >> 4) & 15;
    int chunk = t & 15;

    int row  = chunk * 256 + threadIdx.x;
    int pidx = dir * TOT + bb * NPTS + row;         // global P point id
    int gp   = pidx >> 1, h = pidx & 1;
    float px = pkf[gp * 8 + 0 + h];
    float py = pkf[gp * 8 + 2 + h];
    float pz = pkf[gp * 8 + 4 + h];
    f2 px2 = {-2.0f * px, -2.0f * px};
    f2 py2 = {-2.0f * py, -2.0f * py};
    f2 pz2 = {-2.0f * pz, -2.0f * pz};

    int qbase = (1 - dir) * TOT + bb * NPTS + qseg * QLEN;  // Q point id base
    const float4* Qv = (const float4*)pkf + qbase;          // 16B per point-slot
    Qv += __shfl(0, 0);   // value 0, but marks address divergent -> VMEM loads

    float b0 = 3.4e38f, b1 = 3.4e38f, b2 = 3.4e38f, b3 = 3.4e38f;
    for (int it = 0; it < QLEN / 8; ++it) {
        const float4* q = Qv + it * 8;
        float4 A0 = q[0], B0 = q[1];    // A={x0,x1,y0,y1} B={z0,z1,w0,w1}
        float4 A1 = q[2], B1 = q[3];
        float4 A2 = q[4], B2 = q[5];
        float4 A3 = q[6], B3 = q[7];
        f2 tt;
        {
            f2 xx = {A0.x, A0.y}, yy = {A0.z, A0.w}, zz = {B0.x, B0.y}, ww = {B0.z, B0.w};
            PKFMA(tt, pz2, zz, ww); PKFMA(tt, py2, yy, tt); PKFMA(tt, px2, xx, tt);
            MIN3(b0, tt.x, tt.y);
        }
        {
            f2 xx = {A1.x, A1.y}, yy = {A1.z, A1.w}, zz = {B1.x, B1.y}, ww = {B1.z, B1.w};
            PKFMA(tt, pz2, zz, ww); PKFMA(tt, py2, yy, tt); PKFMA(tt, px2, xx, tt);
            MIN3(b1, tt.x, tt.y);
        }
        {
            f2 xx = {A2.x, A2.y}, yy = {A2.z, A2.w}, zz = {B2.x, B2.y}, ww = {B2.z, B2.w};
            PKFMA(tt, pz2, zz, ww); PKFMA(tt, py2, yy, tt); PKFMA(tt, px2, xx, tt);
            MIN3(b2, tt.x, tt.y);
        }
        {
            f2 xx = {A3.x, A3.y}, yy = {A3.z, A3.w}, zz = {B3.x, B3.y}, ww = {B3.z, B3.w};
            PKFMA(tt, pz2, zz, ww); PKFMA(tt, py2, yy, tt); PKFMA(tt, px2, xx, tt);
            MIN3(b3, tt.x, tt.y);
        }
    }
    float best = fminf(fminf(b0, b1), fminf(b2, b3));
    part[qseg * (2 * TOT) + pidx] = best;           // coalesced
}

// Pass 2: combine the 4 segment partials per point, add |p|^2, block-reduce,
// atomic accumulate the mean.
__global__ __launch_bounds__(256) void chamfer_pass2(const float* __restrict__ part,
                                                     const float* __restrict__ pkf,
                                                     float* __restrict__ out) {
    int gid = blockIdx.x * 256 + threadIdx.x;       // 0..2*TOT-1
    float m0 = part[0 * (2 * TOT) + gid];
    float m1 = part[1 * (2 * TOT) + gid];
    float m2 = part[2 * (2 * TOT) + gid];
    float m3 = part[3 * (2 * TOT) + gid];
    int gp = gid >> 1, h = gid & 1;
    float w = pkf[gp * 8 + 6 + h];
    float m = fminf(fminf(m0, m1), fminf(m2, m3)) + w;

    float s = m;
    #pragma unroll
    for (int off = 32; off; off >>= 1) s += __shfl_down(s, off);
    __shared__ float red[4];
    int lane = threadIdx.x & 63, wid = threadIdx.x >> 6;
    if (lane == 0) red[wid] = s;
    __syncthreads();
    if (threadIdx.x == 0) {
        float tot = (red[0] + red[1]) + (red[2] + red[3]);
        atomicAdd(out, tot * (1.0f / (float)TOT));
    }
}

// ---------------- fallback (no workspace): direct form ----------------
__global__ __launch_bounds__(256) void chamfer_direct(const float* __restrict__ x,
                                                      const float* __restrict__ y,
                                                      float* __restrict__ out) {
    int blk   = blockIdx.x;
    int dir   = blk >> 8;
    int t     = blk & 255;
    int b     = t >> 4;
    int chunk = t & 15;

    const float* __restrict__ P = (dir ? y : x) + (b * NPTS + chunk * 256) * 3;
    const float* __restrict__ Q = (dir ? x : y) + b * NPTS * 3;

    float px = P[threadIdx.x * 3 + 0];
    float py = P[threadIdx.x * 3 + 1];
    float pz = P[threadIdx.x * 3 + 2];

    float b0 = 3.4e38f, b1 = 3.4e38f, b2 = 3.4e38f, b3 = 3.4e38f;
    for (int j = 0; j < NPTS; j += 4) {
        #pragma unroll
        for (int u = 0; u < 4; ++u) {
            float dx = px - Q[(j + u) * 3 + 0];
            float dy = py - Q[(j + u) * 3 + 1];
            float dz = pz - Q[(j + u) * 3 + 2];
            float d  = fmaf(dx, dx, fmaf(dy, dy, dz * dz));
            if (u == 0) b0 = fminf(b0, d);
            if (u == 1) b1 = fminf(b1, d);
            if (u == 2) b2 = fminf(b2, d);
            if (u == 3) b3 = fminf(b3, d);
        }
    }
    float best = fminf(fminf(b0, b1), fminf(b2, b3));

    float v = best;
    #pragma unroll
    for (int off = 32; off; off >>= 1) v += __shfl_down(v, off);
    __shared__ float red[4];
    int lane = threadIdx.x & 63, wid = threadIdx.x >> 6;
    if (lane == 0) red[wid] = v;
    __syncthreads();
    if (threadIdx.x == 0) {
        float s = (red[0] + red[1]) + (red[2] + red[3]);
        atomicAdd(out, s * (1.0f / (float)TOT));
    }
}

__global__ void zero_kernel(float* out) { out[0] = 0.0f; }

extern "C" void kernel_launch(void* const* d_in, const int* in_sizes, int n_in,
                              void* d_out, int out_size, void* d_ws, size_t ws_size,
                              hipStream_t stream) {
    const float* x = (const float*)d_in[0];
    const float* y = (const float*)d_in[1];
    float* out = (float*)d_out;

    size_t pk_bytes   = (size_t)2 * TOT * 4 * sizeof(float);        // 2 MiB
    size_t part_bytes = (size_t)QSEG * 2 * TOT * sizeof(float);     // 2 MiB

    if (ws_size >= pk_bytes + part_bytes) {
        float* pkf  = (float*)d_ws;
        float* part = (float*)((char*)d_ws + pk_bytes);
        hipLaunchKernelGGL(pack_kernel, dim3(2 * TOT / 256), dim3(256), 0, stream,
                           x, y, pkf, out);
        hipLaunchKernelGGL(chamfer_pass1, dim3(512 * QSEG), dim3(256), 0, stream,
                           pkf, part);
        hipLaunchKernelGGL(chamfer_pass2, dim3(2 * TOT / 256), dim3(256), 0, stream,
                           part, pkf, out);
    } else {
        hipLaunchKernelGGL(zero_kernel, dim3(1), dim3(1), 0, stream, out);
        hipLaunchKernelGGL(chamfer_direct, dim3(512), dim3(256), 0, stream, x, y, out);
    }
}

// Round 4
// 86.737 us; speedup vs baseline: 1.3488x; 1.3488x over previous
//
#include <hip/hip_runtime.h>

#define BATCH 16
#define NPTS  4096
#define TOT   (BATCH * NPTS)   // 65536 points per tensor
#define QSEG  4                // Q split into 4 segments
#define QLEN  (NPTS / QSEG)    // 1024 points per segment

typedef float f2 __attribute__((ext_vector_type(2)));
typedef float f4 __attribute__((ext_vector_type(4)));

// ---- packed fp32 with op_sel word-broadcast (VOP3P) ----
// t = { p.lo*q.z + q.w , p.hi*q.z + q.w }   (qzw = {z,w} pair)
#define PK_Z(t, p, qzw) \
    asm("v_pk_fma_f32 %0, %1, %2, %2 op_sel:[0,0,1] op_sel_hi:[1,0,1]" \
        : "=v"(t) : "v"(p), "v"(qzw))
// t += p * broadcast(q.hi)
#define PK_HI(t, p, q) \
    asm("v_pk_fma_f32 %0, %1, %2, %0 op_sel:[0,1,0] op_sel_hi:[1,1,1]" \
        : "+v"(t) : "v"(p), "v"(q))
// t += p * broadcast(q.lo)
#define PK_LO(t, p, q) \
    asm("v_pk_fma_f32 %0, %1, %2, %0 op_sel:[0,0,0] op_sel_hi:[1,0,1]" \
        : "+v"(t) : "v"(p), "v"(q))
// acc = min(acc, u, v)
#define MIN3(acc, u, v) \
    asm("v_min3_f32 %0, %1, %2, %0" : "+v"(acc) : "v"(u), "v"(v))

// distance chain for one Q point (AoS f4) against the packed P pair -> f2 t
#define QDIST(t, qv)                                            \
    do {                                                        \
        f2 _qxy = __builtin_shufflevector(qv, qv, 0, 1);        \
        f2 _qzw = __builtin_shufflevector(qv, qv, 2, 3);        \
        PK_Z(t, pz2, _qzw);                                     \
        PK_HI(t, py2, _qxy);                                    \
        PK_LO(t, px2, _qxy);                                    \
    } while (0)

// Pack {x, y, z, |q|^2} AoS float4 per point; also zero the output scalar.
// pk layout: [2][BATCH][NPTS] f4 ; slot 0 = x tensor, slot 1 = y tensor.
__global__ __launch_bounds__(256) void pack_kernel(const float* __restrict__ x,
                                                   const float* __restrict__ y,
                                                   f4* __restrict__ pk,
                                                   float* __restrict__ out) {
    int idx = blockIdx.x * 256 + threadIdx.x;       // 0 .. 2*TOT-1
    if (idx == 0) out[0] = 0.0f;
    const float* src = (idx < TOT) ? x : y;
    int r = (idx < TOT) ? idx : (idx - TOT);
    float a = src[r * 3 + 0];
    float b = src[r * 3 + 1];
    float c = src[r * 3 + 2];
    f4 v = {a, b, c, fmaf(a, a, fmaf(b, b, c * c))};
    pk[idx] = v;
}

// Pass 1: block = (dir, batch, 256-pair chunk, q-segment). Each thread owns
// TWO P points (packed in register pairs) and scans its 1024-point Q segment.
// Per Q point: 3 v_pk_fma_f32 (op_sel broadcasts Q words); per 2 Q: 2 v_min3.
// => 2.0 VALU/pair, no repacking movs. Q loads forced to VMEM.
__global__ __launch_bounds__(256, 4) void chamfer_pass1(const float* __restrict__ pkf,
                                                        float* __restrict__ part) {
    int blk   = blockIdx.x;        // 0..1023
    int qseg  = blk & 3;
    int t     = blk >> 2;          // 0..255
    int dir   = t >> 7;            // 0: P=x,Q=y ; 1: P=y,Q=x
    int bb    = (t >> 3) & 15;     // batch
    int chunk = t & 7;             // 8 chunks of 256 pairs

    const f4* __restrict__ pk = (const f4*)pkf;

    int pp    = chunk * 256 + threadIdx.x;              // pair id in (dir,b)
    int pidx0 = dir * TOT + bb * NPTS + 2 * pp;         // even P point id

    f4 a = pk[pidx0];
    f4 b = pk[pidx0 + 1];
    f2 px2 = {-2.0f * a.x, -2.0f * b.x};
    f2 py2 = {-2.0f * a.y, -2.0f * b.y};
    f2 pz2 = {-2.0f * a.z, -2.0f * b.z};

    int qbase = (1 - dir) * TOT + bb * NPTS + qseg * QLEN;
    const f4* __restrict__ qp = pk + qbase;
    qp += __shfl(0, 0);   // value 0; marks address divergent -> VMEM (not SMEM)

    float acc0 = 3.4e38f, acc1 = 3.4e38f;
    for (int it = 0; it < QLEN / 8; ++it) {
        f4 q0 = qp[0], q1 = qp[1], q2 = qp[2], q3 = qp[3];
        f4 q4 = qp[4], q5 = qp[5], q6 = qp[6], q7 = qp[7];
        qp += 8;
        f2 ta, tb;
        QDIST(ta, q0); QDIST(tb, q1);
        MIN3(acc0, ta.x, tb.x); MIN3(acc1, ta.y, tb.y);
        QDIST(ta, q2); QDIST(tb, q3);
        MIN3(acc0, ta.x, tb.x); MIN3(acc1, ta.y, tb.y);
        QDIST(ta, q4); QDIST(tb, q5);
        MIN3(acc0, ta.x, tb.x); MIN3(acc1, ta.y, tb.y);
        QDIST(ta, q6); QDIST(tb, q7);
        MIN3(acc0, ta.x, tb.x); MIN3(acc1, ta.y, tb.y);
    }

    // coalesced f2 store: part[qseg][pidx0 .. pidx0+1]
    f2 res = {acc0, acc1};
    *(f2*)(part + qseg * (2 * TOT) + pidx0) = res;
}

// Pass 2: combine the 4 segment partials per point, add |p|^2, block-reduce,
// atomic accumulate the mean.
__global__ __launch_bounds__(256) void chamfer_pass2(const float* __restrict__ part,
                                                     const float* __restrict__ pkf,
                                                     float* __restrict__ out) {
    int gid = blockIdx.x * 256 + threadIdx.x;       // 0..2*TOT-1
    float m0 = part[0 * (2 * TOT) + gid];
    float m1 = part[1 * (2 * TOT) + gid];
    float m2 = part[2 * (2 * TOT) + gid];
    float m3 = part[3 * (2 * TOT) + gid];
    float w  = pkf[gid * 4 + 3];
    float m = fminf(fminf(m0, m1), fminf(m2, m3)) + w;

    float s = m;
    #pragma unroll
    for (int off = 32; off; off >>= 1) s += __shfl_down(s, off);
    __shared__ float red[4];
    int lane = threadIdx.x & 63, wid = threadIdx.x >> 6;
    if (lane == 0) red[wid] = s;
    __syncthreads();
    if (threadIdx.x == 0) {
        float tot = (red[0] + red[1]) + (red[2] + red[3]);
        atomicAdd(out, tot * (1.0f / (float)TOT));
    }
}

// ---------------- fallback (no workspace): direct form ----------------
__global__ __launch_bounds__(256) void chamfer_direct(const float* __restrict__ x,
                                                      const float* __restrict__ y,
                                                      float* __restrict__ out) {
    int blk   = blockIdx.x;
    int dir   = blk >> 8;
    int t     = blk & 255;
    int b     = t >> 4;
    int chunk = t & 15;

    const float* __restrict__ P = (dir ? y : x) + (b * NPTS + chunk * 256) * 3;
    const float* __restrict__ Q = (dir ? x : y) + b * NPTS * 3;

    float px = P[threadIdx.x * 3 + 0];
    float py = P[threadIdx.x * 3 + 1];
    float pz = P[threadIdx.x * 3 + 2];

    float b0 = 3.4e38f, b1 = 3.4e38f, b2 = 3.4e38f, b3 = 3.4e38f;
    for (int j = 0; j < NPTS; j += 4) {
        #pragma unroll
        for (int u = 0; u < 4; ++u) {
            float dx = px - Q[(j + u) * 3 + 0];
            float dy = py - Q[(j + u) * 3 + 1];
            float dz = pz - Q[(j + u) * 3 + 2];
            float d  = fmaf(dx, dx, fmaf(dy, dy, dz * dz));
            if (u == 0) b0 = fminf(b0, d);
            if (u == 1) b1 = fminf(b1, d);
            if (u == 2) b2 = fminf(b2, d);
            if (u == 3) b3 = fminf(b3, d);
        }
    }
    float best = fminf(fminf(b0, b1), fminf(b2, b3));

    float v = best;
    #pragma unroll
    for (int off = 32; off; off >>= 1) v += __shfl_down(v, off);
    __shared__ float red[4];
    int lane = threadIdx.x & 63, wid = threadIdx.x >> 6;
    if (lane == 0) red[wid] = v;
    __syncthreads();
    if (threadIdx.x == 0) {
        float s = (red[0] + red[1]) + (red[2] + red[3]);
        atomicAdd(out, s * (1.0f / (float)TOT));
    }
}

__global__ void zero_kernel(float* out) { out[0] = 0.0f; }

extern "C" void kernel_launch(void* const* d_in, const int* in_sizes, int n_in,
                              void* d_out, int out_size, void* d_ws, size_t ws_size,
                              hipStream_t stream) {
    const float* x = (const float*)d_in[0];
    const float* y = (const float*)d_in[1];
    float* out = (float*)d_out;

    size_t pk_bytes   = (size_t)2 * TOT * 4 * sizeof(float);        // 2 MiB
    size_t part_bytes = (size_t)QSEG * 2 * TOT * sizeof(float);     // 2 MiB

    if (ws_size >= pk_bytes + part_bytes) {
        float* pkf  = (float*)d_ws;
        float* part = (float*)((char*)d_ws + pk_bytes);
        hipLaunchKernelGGL(pack_kernel, dim3(2 * TOT / 256), dim3(256), 0, stream,
                           x, y, (f4*)pkf, out);
        hipLaunchKernelGGL(chamfer_pass1, dim3(1024), dim3(256), 0, stream,
                           pkf, part);
        hipLaunchKernelGGL(chamfer_pass2, dim3(2 * TOT / 256), dim3(256), 0, stream,
                           part, pkf, out);
    } else {
        hipLaunchKernelGGL(zero_kernel, dim3(1), dim3(1), 0, stream, out);
        hipLaunchKernelGGL(chamfer_direct, dim3(512), dim3(256), 0, stream, x, y, out);
    }
}